// Round 17
// baseline (7528.025 us; speedup 1.0000x reference)
//
#include <hip/hip_runtime.h>

// LSTM B=32 T=2048 I=H=512. out = h_T [1,32,512] f32.
// R11 protocol verbatim, rendezvous width halved: 16 recurrence blocks x 512
// threads (block k owns units [32k,32k+32), 128 gate rows; wave w owns rows
// w*16..+16 -> wf[16]). Same staging/zl/gate structure scaled; z bit-identical
// to R11. GEMM on blocks 16..255 (512 thr: all load, waves 0-3 compute).

#define T_FULL 2048
#define CHUNK  128
#define NCHUNK 16
#define NBLK   16
#define NGEMM  240   // 256 - NBLK

typedef float  f32x4 __attribute__((ext_vector_type(4)));
typedef short  s16x8 __attribute__((ext_vector_type(8)));
typedef unsigned int u32;

#define MFMA16(a,b,c) __builtin_amdgcn_mfma_f32_16x16x32_bf16((a),(b),(c),0,0,0)

__device__ inline unsigned short f2bf(float f){
  unsigned u = __builtin_bit_cast(unsigned, f);
  u += 0x7fffu + ((u>>16)&1u);          // RNE
  return (unsigned short)(u>>16);
}
__device__ inline float bf2f(unsigned short s){
  unsigned u = ((unsigned)s)<<16;
  return __builtin_bit_cast(float, u);
}
__device__ inline float sigmoid_(float x){
  x = fminf(fmaxf(x,-30.f),30.f);
  return 1.f/(1.f + __expf(-x));
}
__device__ inline float tanh_(float x){
  x = fminf(fmaxf(x,-15.f),15.f);
  float e = __expf(2.f*x);
  return (e-1.f)/(e+1.f);
}

// ---------------- x_proj GEMM tile (64M x 64N, K=512), 512 threads ----------
// All 512 threads load; waves 0-3 run MFMA + epilogue (waves 4-7 park at
// barriers). smem: At at +0 (17408B), Bt at +17408.
__device__ void gemm_tile(const float* __restrict__ x, const float* __restrict__ Wih,
                          const float* __restrict__ bih, const float* __restrict__ bhh,
                          unsigned short* __restrict__ xp, int t0, int nx, int ny,
                          char* smem)
{
  unsigned short* At = (unsigned short*)smem;
  unsigned short* Bt = (unsigned short*)(smem + 17408);
  const int tid = threadIdx.x, lane = tid&63, w = tid>>6;
  const int l15 = lane&15, l4 = lane>>4;
  const int n0 = nx*64, m0 = ny*64;
  const int mbase = (w&1)*32, nbase = ((w>>1)&1)*32;

  f32x4 acc[2][2];
  #pragma unroll
  for (int mi=0; mi<2; ++mi)
    #pragma unroll
    for (int ni=0; ni<2; ++ni)
      acc[mi][ni] = (f32x4){0.f,0.f,0.f,0.f};

  for (int kb=0; kb<4; ++kb){
    #pragma unroll
    for (int it=0; it<2; ++it){
      int grp = it*512 + tid;            // 0..1023
      int row = grp>>4, c8 = (grp&15)*8; // 16 groups of 8 per row
      {
        int m = m0 + row;
        size_t t = (size_t)t0 + (m>>5), b = (size_t)(m&31);
        const float* src = x + ((b*2048 + t)<<9) + kb*128 + c8;
        f32x4 v0 = *(const f32x4*)src, v1 = *(const f32x4*)(src+4);
        unsigned short* d = &At[row*136 + c8];
        d[0]=f2bf(v0[0]); d[1]=f2bf(v0[1]); d[2]=f2bf(v0[2]); d[3]=f2bf(v0[3]);
        d[4]=f2bf(v1[0]); d[5]=f2bf(v1[1]); d[6]=f2bf(v1[2]); d[7]=f2bf(v1[3]);
      }
      {
        const float* src = Wih + (size_t)(n0+row)*512 + kb*128 + c8;
        f32x4 v0 = *(const f32x4*)src, v1 = *(const f32x4*)(src+4);
        unsigned short* d = &Bt[row*136 + c8];
        d[0]=f2bf(v0[0]); d[1]=f2bf(v0[1]); d[2]=f2bf(v0[2]); d[3]=f2bf(v0[3]);
        d[4]=f2bf(v1[0]); d[5]=f2bf(v1[1]); d[6]=f2bf(v1[2]); d[7]=f2bf(v1[3]);
      }
    }
    __syncthreads();
    if (w < 4){
      #pragma unroll
      for (int ks=0; ks<4; ++ks){
        s16x8 af0 = *(const s16x8*)&At[(mbase+   l15)*136 + ks*32 + l4*8];
        s16x8 af1 = *(const s16x8*)&At[(mbase+16+l15)*136 + ks*32 + l4*8];
        s16x8 bf0 = *(const s16x8*)&Bt[(nbase+   l15)*136 + ks*32 + l4*8];
        s16x8 bf1 = *(const s16x8*)&Bt[(nbase+16+l15)*136 + ks*32 + l4*8];
        acc[0][0] = MFMA16(af0,bf0,acc[0][0]);
        acc[0][1] = MFMA16(af0,bf1,acc[0][1]);
        acc[1][0] = MFMA16(af1,bf0,acc[1][0]);
        acc[1][1] = MFMA16(af1,bf1,acc[1][1]);
      }
    }
    __syncthreads();
  }
  if (w < 4){
    #pragma unroll
    for (int ni=0; ni<2; ++ni){
      int col = n0 + nbase + ni*16 + l15;
      float bias = bih[col] + bhh[col];
      #pragma unroll
      for (int mi=0; mi<2; ++mi){
        #pragma unroll
        for (int r=0; r<4; ++r){
          int mrow = m0 + mbase + mi*16 + l4*4 + r;
          xp[(size_t)mrow*2048 + col] = f2bf(acc[mi][ni][r] + bias);
        }
      }
    }
  }
}

// ---------------- Phase 1 standalone (chunk 0 only) ----------------
__global__ __launch_bounds__(512) void lstm_p1(
    const float* __restrict__ x, const float* __restrict__ Wih,
    const float* __restrict__ bih, const float* __restrict__ bhh,
    unsigned short* __restrict__ xp, int t0)
{
  __shared__ __align__(16) char smem[34816];
  gemm_tile(x, Wih, bih, bhh, xp, t0, blockIdx.x, blockIdx.y, smem);
}

// ---------------- Fused: recurrence (blocks 0..15) + next-chunk GEMM --------
// Hbuf: 2 slots x [batch 32][unit 512] bf16. flag[k*32]: u32 = t+1.
__global__ __launch_bounds__(512,1) void lstm_fused(
    const unsigned short* __restrict__ xp_cur,
    const float* __restrict__ x, const float* __restrict__ Wih,
    const float* __restrict__ bih, const float* __restrict__ bhh,
    unsigned short* __restrict__ xp_next, const float* __restrict__ Whh,
    unsigned short* __restrict__ Hbuf, float* __restrict__ cst,
    u32* __restrict__ flag, float* __restrict__ out, int t0, int do_gemm)
{
  __shared__ __align__(16) char smem[49664];   // recur: Hl 32KB + zl 16.5KB; gemm: At/Bt
  const int bid = blockIdx.x;

  if (bid >= NBLK){
    if (do_gemm){
      const int t0n = t0 + CHUNK;
      for (int tile = bid - NBLK; tile < 32*(CHUNK*32/64); tile += NGEMM)
        gemm_tile(x, Wih, bih, bhh, xp_next, t0n, tile & 31, tile >> 5, smem);
    }
    return;
  }

  // ---- recurrence: R11 protocol, 16-block geometry ----
  char* Hl = smem;                              // 32KB swizzled H
  float (*zl)[132] = (float(*)[132])(smem + 32768);  // [32 batch][128+4]
  const int k = bid;
  const int tid = threadIdx.x;
  const int lane = tid & 63, w = tid >> 6;      // w 0..7
  const int l15 = lane & 15, l4 = lane >> 4;

  // W_hh B-fragments: wave w owns block gate rows lrow = w*16+l15 (0..127);
  // lrow -> (gate lrow>>5, unit k*32 + (lrow&31)).
  s16x8 wf[16];
  {
    const int lrow = w*16 + l15;
    const int grow = (lrow>>5)*512 + k*32 + (lrow&31);
    const float* wr = Whh + (size_t)grow*512;
    #pragma unroll
    for (int ks=0; ks<16; ++ks){
      const float* s = wr + ks*32 + l4*8;
      f32x4 v0 = *(const f32x4*)s, v1 = *(const f32x4*)(s+4);
      s16x8 tv;
      tv[0]=(short)f2bf(v0[0]); tv[1]=(short)f2bf(v0[1]);
      tv[2]=(short)f2bf(v0[2]); tv[3]=(short)f2bf(v0[3]);
      tv[4]=(short)f2bf(v1[0]); tv[5]=(short)f2bf(v1[1]);
      tv[6]=(short)f2bf(v1[2]); tv[7]=(short)f2bf(v1[3]);
      wf[ks] = tv;
    }
  }

  const int s_ = tid >> 4;        // batch 0..31
  const int a_ = tid & 15;        // unit-pair 0..15
  const int ucol = k*32 + 2*a_;   // global hidden col of first unit
  float c0 = cst[s_*512 + ucol], c1 = cst[s_*512 + ucol + 1];

  #define PLOAD() ((lane < NBLK) \
      ? __hip_atomic_load(&flag[lane<<5], __ATOMIC_RELAXED, __HIP_MEMORY_SCOPE_AGENT) \
      : 0xffffffffu)

  for (int tt=0; tt<CHUNK; ++tt){
    const int t = t0 + tt;

    // prefetch xp: this thread's 2 units x 4 gates (independent of poll)
    unsigned int xq[4];
    #pragma unroll
    for (int g=0; g<4; ++g)
      xq[g] = *(const unsigned int*)(xp_cur + (size_t)(tt*32 + s_)*2048 + g*512 + ucol);

    if (t > 0){
      if (w == 0){
        // 2-deep pipelined poll (R11)
        u32 va = PLOAD();
        for (;;){
          u32 vb = PLOAD();
          if (__all(va >= (u32)t)) break;
          va = PLOAD();
          if (__all(vb >= (u32)t)) break;
        }
        __builtin_amdgcn_fence(__ATOMIC_ACQUIRE, "agent");
      }
      __syncthreads();
    }

    // stage H_{t-1} (slot (t-1)&1) into swizzled LDS
    {
      const char* hsrc = (const char*)(Hbuf + ((t+1)&1)*(32*512));
      #pragma unroll
      for (int it=0; it<4; ++it){
        int off = (it*512 + tid)*16;        // 0..32K
        f32x4 v = *(const f32x4*)(hsrc + off);
        *(f32x4*)&Hl[off ^ (((off>>10)&7)<<4)] = v;
      }
    }
    __syncthreads();

    // z = H @ Wslice^T : 2 m-tiles (batches 0-15 / 16-31) x wave's n-tile
    f32x4 acc0 = (f32x4){0.f,0.f,0.f,0.f};
    f32x4 acc1 = (f32x4){0.f,0.f,0.f,0.f};
    {
      const int swz = (l15&7)<<4;           // (16+l15)&7 == l15&7
      const int rb0 = l15<<10, rb1 = (16+l15)<<10;
      #pragma unroll
      for (int ks=0; ks<16; ++ks){
        int cb = ks*64 + l4*16;
        s16x8 af0 = *(const s16x8*)&Hl[rb0 | (cb ^ swz)];
        s16x8 af1 = *(const s16x8*)&Hl[rb1 | (cb ^ swz)];
        acc0 = MFMA16(af0, wf[ks], acc0);
        acc1 = MFMA16(af1, wf[ks], acc1);
      }
    }
    #pragma unroll
    for (int r=0; r<4; ++r){
      zl[     l4*4 + r][w*16 + l15] = acc0[r];
      zl[16 + l4*4 + r][w*16 + l15] = acc1[r];
    }
    __syncthreads();

    // gates for (batch s_, units 2a_, 2a_+1); zl col = gate*32 + unit_local
    float zi0 = zl[s_][  0 + 2*a_    ] + bf2f((unsigned short)(xq[0]&0xffffu));
    float zi1 = zl[s_][  0 + 2*a_ + 1] + bf2f((unsigned short)(xq[0]>>16));
    float zf0 = zl[s_][ 32 + 2*a_    ] + bf2f((unsigned short)(xq[1]&0xffffu));
    float zf1 = zl[s_][ 32 + 2*a_ + 1] + bf2f((unsigned short)(xq[1]>>16));
    float zg0 = zl[s_][ 64 + 2*a_    ] + bf2f((unsigned short)(xq[2]&0xffffu));
    float zg1 = zl[s_][ 64 + 2*a_ + 1] + bf2f((unsigned short)(xq[2]>>16));
    float zo0 = zl[s_][ 96 + 2*a_    ] + bf2f((unsigned short)(xq[3]&0xffffu));
    float zo1 = zl[s_][ 96 + 2*a_ + 1] + bf2f((unsigned short)(xq[3]>>16));

    float i0 = sigmoid_(zi0), f0 = sigmoid_(zf0), g0 = tanh_(zg0), o0 = sigmoid_(zo0);
    float i1 = sigmoid_(zi1), f1 = sigmoid_(zf1), g1 = tanh_(zg1), o1 = sigmoid_(zo1);
    c0 = f0*c0 + i0*g0;
    c1 = f1*c1 + i1*g1;
    float h0 = o0 * tanh_(c0);
    float h1 = o1 * tanh_(c1);

    // publish h (slot t&1): relaxed agent atomics
    {
      unsigned short* hdst = Hbuf + (t&1)*(32*512);
      unsigned int hp = (unsigned int)f2bf(h0) | ((unsigned int)f2bf(h1)<<16);
      __hip_atomic_store((unsigned int*)((char*)hdst + s_*1024 + ucol*2), hp,
                         __ATOMIC_RELAXED, __HIP_MEMORY_SCOPE_AGENT);
    }
    if (t == T_FULL-1){
      out[s_*512 + ucol    ] = h0;
      out[s_*512 + ucol + 1] = h1;
    }

    // drain our stores (global visibility), block-wide, then flag
    asm volatile("s_waitcnt vmcnt(0)" ::: "memory");
    __syncthreads();
    if (tid == 0)
      __hip_atomic_store(&flag[k<<5], (unsigned)(t+1),
                         __ATOMIC_RELAXED, __HIP_MEMORY_SCOPE_AGENT);
  }

  #undef PLOAD

  cst[s_*512 + ucol    ] = c0;
  cst[s_*512 + ucol + 1] = c1;
}

// ---------------- launch ----------------
extern "C" void kernel_launch(void* const* d_in, const int* in_sizes, int n_in,
                              void* d_out, int out_size, void* d_ws, size_t ws_size,
                              hipStream_t stream)
{
  const float* x   = (const float*)d_in[0];
  const float* Wih = (const float*)d_in[1];
  const float* Whh = (const float*)d_in[2];
  const float* bih = (const float*)d_in[3];
  const float* bhh = (const float*)d_in[4];
  float* out = (float*)d_out;

  char* ws = (char*)d_ws;
  const size_t XPB = (size_t)CHUNK*32*2048*2;          // 16,777,216 per buffer
  unsigned short* xp0  = (unsigned short*)ws;
  unsigned short* xp1  = (unsigned short*)(ws + XPB);
  unsigned short* Hbuf = (unsigned short*)(ws + 2*XPB);            // 2*32KB = 65536
  float*          cst  = (float*)(ws + 2*XPB + 65536);             // 64KB
  u32*            flag = (u32*)(ws + 2*XPB + 65536 + 65536);       // 16*128B = 2KB

  // zero Hbuf (h_0 = 0) + c-state + flags; every launch (replay-safe)
  (void)hipMemsetAsync(Hbuf, 0, 65536 + 65536 + 4096, stream);

  lstm_p1<<<dim3(32, CHUNK*32/64), 512, 0, stream>>>(x, Wih, bih, bhh, xp0, 0);

  for (int c=0; c<NCHUNK; ++c){
    unsigned short* xc = (c & 1) ? xp1 : xp0;
    unsigned short* xn = (c & 1) ? xp0 : xp1;
    lstm_fused<<<256, 512, 0, stream>>>(xc, x, Wih, bih, bhh, xn, Whh,
                                        Hbuf, cst, flag, out, c*CHUNK,
                                        (c < NCHUNK-1) ? 1 : 0);
  }
}

// Round 18
// 6044.909 us; speedup vs baseline: 1.2453x; 1.2453x over previous
//
#include <hip/hip_runtime.h>

// LSTM B=32 T=2048 I=H=512. out = h_T [1,32,512] f32.
// CHAMPION (R11, best measured 6.13 ms): fused GEMM on blocks 32..255 +
// R3-protocol recurrence on blocks 0..31 (block flags, wave0 2-deep poll,
// ONE acquire fence, cached swizzled LDS stage, zl-LDS gates,
// drain+barrier+tid0 flag). 3.0 us/step = structural cross-XCD latency floor
// (2048 serial MALL rendezvous); 14 protocol variants bracketed and lost.

#define T_FULL 2048
#define CHUNK  128
#define NCHUNK 16
#define NBLK   32
#define NGEMM  224   // 256 - NBLK

typedef float  f32x4 __attribute__((ext_vector_type(4)));
typedef short  s16x8 __attribute__((ext_vector_type(8)));
typedef unsigned int u32;

#define MFMA16(a,b,c) __builtin_amdgcn_mfma_f32_16x16x32_bf16((a),(b),(c),0,0,0)

__device__ inline unsigned short f2bf(float f){
  unsigned u = __builtin_bit_cast(unsigned, f);
  u += 0x7fffu + ((u>>16)&1u);          // RNE
  return (unsigned short)(u>>16);
}
__device__ inline float bf2f(unsigned short s){
  unsigned u = ((unsigned)s)<<16;
  return __builtin_bit_cast(float, u);
}
__device__ inline float sigmoid_(float x){
  x = fminf(fmaxf(x,-30.f),30.f);
  return 1.f/(1.f + __expf(-x));
}
__device__ inline float tanh_(float x){
  x = fminf(fmaxf(x,-15.f),15.f);
  float e = __expf(2.f*x);
  return (e-1.f)/(e+1.f);
}

// ---------------- x_proj GEMM tile (64M x 64N, K=512) ----------------
__device__ void gemm_tile(const float* __restrict__ x, const float* __restrict__ Wih,
                          const float* __restrict__ bih, const float* __restrict__ bhh,
                          unsigned short* __restrict__ xp, int t0, int nx, int ny,
                          char* smem)
{
  unsigned short* At = (unsigned short*)smem;
  unsigned short* Bt = (unsigned short*)(smem + 17408);
  const int tid = threadIdx.x, lane = tid&63, w = tid>>6;
  const int l15 = lane&15, l4 = lane>>4;
  const int n0 = nx*64, m0 = ny*64;
  const int mbase = (w&1)*32, nbase = (w>>1)*32;

  f32x4 acc[2][2];
  #pragma unroll
  for (int mi=0; mi<2; ++mi)
    #pragma unroll
    for (int ni=0; ni<2; ++ni)
      acc[mi][ni] = (f32x4){0.f,0.f,0.f,0.f};

  for (int kb=0; kb<4; ++kb){
    #pragma unroll
    for (int it=0; it<4; ++it){
      int grp = it*256 + tid;
      int row = grp>>4, c8 = (grp&15)*8;
      {
        int m = m0 + row;
        size_t t = (size_t)t0 + (m>>5), b = (size_t)(m&31);
        const float* src = x + ((b*2048 + t)<<9) + kb*128 + c8;
        f32x4 v0 = *(const f32x4*)src, v1 = *(const f32x4*)(src+4);
        unsigned short* d = &At[row*136 + c8];
        d[0]=f2bf(v0[0]); d[1]=f2bf(v0[1]); d[2]=f2bf(v0[2]); d[3]=f2bf(v0[3]);
        d[4]=f2bf(v1[0]); d[5]=f2bf(v1[1]); d[6]=f2bf(v1[2]); d[7]=f2bf(v1[3]);
      }
      {
        const float* src = Wih + (size_t)(n0+row)*512 + kb*128 + c8;
        f32x4 v0 = *(const f32x4*)src, v1 = *(const f32x4*)(src+4);
        unsigned short* d = &Bt[row*136 + c8];
        d[0]=f2bf(v0[0]); d[1]=f2bf(v0[1]); d[2]=f2bf(v0[2]); d[3]=f2bf(v0[3]);
        d[4]=f2bf(v1[0]); d[5]=f2bf(v1[1]); d[6]=f2bf(v1[2]); d[7]=f2bf(v1[3]);
      }
    }
    __syncthreads();
    #pragma unroll
    for (int ks=0; ks<4; ++ks){
      s16x8 af0 = *(const s16x8*)&At[(mbase+   l15)*136 + ks*32 + l4*8];
      s16x8 af1 = *(const s16x8*)&At[(mbase+16+l15)*136 + ks*32 + l4*8];
      s16x8 bf0 = *(const s16x8*)&Bt[(nbase+   l15)*136 + ks*32 + l4*8];
      s16x8 bf1 = *(const s16x8*)&Bt[(nbase+16+l15)*136 + ks*32 + l4*8];
      acc[0][0] = MFMA16(af0,bf0,acc[0][0]);
      acc[0][1] = MFMA16(af0,bf1,acc[0][1]);
      acc[1][0] = MFMA16(af1,bf0,acc[1][0]);
      acc[1][1] = MFMA16(af1,bf1,acc[1][1]);
    }
    __syncthreads();
  }
  #pragma unroll
  for (int ni=0; ni<2; ++ni){
    int col = n0 + nbase + ni*16 + l15;
    float bias = bih[col] + bhh[col];
    #pragma unroll
    for (int mi=0; mi<2; ++mi){
      #pragma unroll
      for (int r=0; r<4; ++r){
        int mrow = m0 + mbase + mi*16 + l4*4 + r;
        xp[(size_t)mrow*2048 + col] = f2bf(acc[mi][ni][r] + bias);
      }
    }
  }
}

// ---------------- Phase 1 standalone (chunk 0 only) ----------------
__global__ __launch_bounds__(256) void lstm_p1(
    const float* __restrict__ x, const float* __restrict__ Wih,
    const float* __restrict__ bih, const float* __restrict__ bhh,
    unsigned short* __restrict__ xp, int t0)
{
  __shared__ __align__(16) char smem[34816];
  gemm_tile(x, Wih, bih, bhh, xp, t0, blockIdx.x, blockIdx.y, smem);
}

// ---------------- Fused: R3 recurrence (blocks 0..31) + next-chunk GEMM -----
// Hbuf: 2 slots x [batch 32][unit 512] bf16. flag[k*32]: u32 = t+1.
__global__ __launch_bounds__(256,1) void lstm_fused(
    const unsigned short* __restrict__ xp_cur,
    const float* __restrict__ x, const float* __restrict__ Wih,
    const float* __restrict__ bih, const float* __restrict__ bhh,
    unsigned short* __restrict__ xp_next, const float* __restrict__ Whh,
    unsigned short* __restrict__ Hbuf, float* __restrict__ cst,
    u32* __restrict__ flag, float* __restrict__ out, int t0, int do_gemm)
{
  __shared__ __align__(16) char smem[41472];   // recur: Hl 32KB + zl 8.5KB; gemm: At/Bt
  const int bid = blockIdx.x;

  if (bid >= NBLK){
    if (do_gemm){
      const int t0n = t0 + CHUNK;
      for (int tile = bid - NBLK; tile < 32*(CHUNK*32/64); tile += NGEMM)
        gemm_tile(x, Wih, bih, bhh, xp_next, t0n, tile & 31, tile >> 5, smem);
    }
    return;
  }

  // ---- R3 recurrence, byte-exact except the 2-deep pipelined poll ----
  char* Hl = smem;                            // 32KB
  float (*zl)[68] = (float(*)[68])(smem + 32768);
  const int k = bid;
  const int tid = threadIdx.x;
  const int lane = tid & 63, w = tid >> 6;
  const int l15 = lane & 15, l4 = lane >> 4;
  const int mt = w & 1, gp = w >> 1;

  // Preload W_hh fragments (bf16) into registers: wf[nt][ks]
  s16x8 wf[2][16];
  #pragma unroll
  for (int nt=0; nt<2; ++nt){
    int lrow = gp*32 + nt*16 + l15;                       // 0..63 local gate row
    int grow = (lrow>>4)*512 + k*16 + (lrow&15);          // global gate row
    const float* wr = Whh + (size_t)grow*512;
    #pragma unroll
    for (int ks=0; ks<16; ++ks){
      const float* s = wr + ks*32 + l4*8;
      f32x4 v0 = *(const f32x4*)s, v1 = *(const f32x4*)(s+4);
      s16x8 tv;
      tv[0]=(short)f2bf(v0[0]); tv[1]=(short)f2bf(v0[1]);
      tv[2]=(short)f2bf(v0[2]); tv[3]=(short)f2bf(v0[3]);
      tv[4]=(short)f2bf(v1[0]); tv[5]=(short)f2bf(v1[1]);
      tv[6]=(short)f2bf(v1[2]); tv[7]=(short)f2bf(v1[3]);
      wf[nt][ks] = tv;
    }
  }

  const int s_ = tid >> 3, a_ = tid & 7;    // seq, unit-pair index
  const int ucol = k*16 + 2*a_;             // global hidden col of first unit
  float c0 = cst[s_*512 + ucol], c1 = cst[s_*512 + ucol + 1];

  for (int tt=0; tt<CHUNK; ++tt){
    const int t = t0 + tt;

    // prefetch xp for this thread's 2 units x 4 gates (independent of poll)
    unsigned int xq[4];
    #pragma unroll
    for (int g=0; g<4; ++g)
      xq[g] = *(const unsigned int*)(xp_cur + (size_t)(tt*32 + s_)*2048 + g*512 + ucol);

    if (t > 0){
      if (w == 0){
        // 2-deep pipelined poll: two independent flag loads in flight
        u32 va = (lane < NBLK)
          ? __hip_atomic_load(&flag[lane<<5], __ATOMIC_RELAXED, __HIP_MEMORY_SCOPE_AGENT)
          : 0xffffffffu;
        for (;;){
          u32 vb = (lane < NBLK)
            ? __hip_atomic_load(&flag[lane<<5], __ATOMIC_RELAXED, __HIP_MEMORY_SCOPE_AGENT)
            : 0xffffffffu;
          if (__all(va >= (u32)t)) break;
          va = (lane < NBLK)
            ? __hip_atomic_load(&flag[lane<<5], __ATOMIC_RELAXED, __HIP_MEMORY_SCOPE_AGENT)
            : 0xffffffffu;
          if (__all(vb >= (u32)t)) break;
        }
        __builtin_amdgcn_fence(__ATOMIC_ACQUIRE, "agent");
      }
      __syncthreads();
    }

    // stage H_{t-1} (slot (t-1)&1) into swizzled LDS
    {
      const char* hsrc = (const char*)(Hbuf + ((t+1)&1)*(32*512));
      #pragma unroll
      for (int it=0; it<8; ++it){
        int off = (it*256 + tid)*16;        // 0..32K
        f32x4 v = *(const f32x4*)(hsrc + off);
        *(f32x4*)&Hl[off ^ (((off>>10)&7)<<4)] = v;
      }
    }
    __syncthreads();

    // z-slice = H @ Wslice^T
    f32x4 acc0 = (f32x4){0.f,0.f,0.f,0.f};
    f32x4 acc1 = (f32x4){0.f,0.f,0.f,0.f};
    {
      const int row = mt*16 + l15;
      const int swz = (row&7)<<4;
      const int rbase = row<<10;
      #pragma unroll
      for (int ks=0; ks<16; ++ks){
        int cb = ks*64 + l4*16;
        s16x8 af = *(const s16x8*)&Hl[rbase | (cb ^ swz)];
        acc0 = MFMA16(af, wf[0][ks], acc0);
        acc1 = MFMA16(af, wf[1][ks], acc1);
      }
    }
    #pragma unroll
    for (int r=0; r<4; ++r){
      zl[mt*16 + l4*4 + r][gp*32 +      l15] = acc0[r];
      zl[mt*16 + l4*4 + r][gp*32 + 16 + l15] = acc1[r];
    }
    __syncthreads();

    // gates for (s_, units 2a_ and 2a_+1)
    float zi0 = zl[s_][ 0 + 2*a_    ] + bf2f((unsigned short)(xq[0]&0xffffu));
    float zi1 = zl[s_][ 0 + 2*a_ + 1] + bf2f((unsigned short)(xq[0]>>16));
    float zf0 = zl[s_][16 + 2*a_    ] + bf2f((unsigned short)(xq[1]&0xffffu));
    float zf1 = zl[s_][16 + 2*a_ + 1] + bf2f((unsigned short)(xq[1]>>16));
    float zg0 = zl[s_][32 + 2*a_    ] + bf2f((unsigned short)(xq[2]&0xffffu));
    float zg1 = zl[s_][32 + 2*a_ + 1] + bf2f((unsigned short)(xq[2]>>16));
    float zo0 = zl[s_][48 + 2*a_    ] + bf2f((unsigned short)(xq[3]&0xffffu));
    float zo1 = zl[s_][48 + 2*a_ + 1] + bf2f((unsigned short)(xq[3]>>16));

    float i0 = sigmoid_(zi0), f0 = sigmoid_(zf0), g0 = tanh_(zg0), o0 = sigmoid_(zo0);
    float i1 = sigmoid_(zi1), f1 = sigmoid_(zf1), g1 = tanh_(zg1), o1 = sigmoid_(zo1);
    c0 = f0*c0 + i0*g0;
    c1 = f1*c1 + i1*g1;
    float h0 = o0 * tanh_(c0);
    float h1 = o1 * tanh_(c1);

    // publish h (slot t&1): relaxed agent atomics
    {
      unsigned short* hdst = Hbuf + (t&1)*(32*512);
      unsigned int hp = (unsigned int)f2bf(h0) | ((unsigned int)f2bf(h1)<<16);
      __hip_atomic_store((unsigned int*)((char*)hdst + s_*1024 + ucol*2), hp,
                         __ATOMIC_RELAXED, __HIP_MEMORY_SCOPE_AGENT);
    }
    if (t == T_FULL-1){
      out[s_*512 + ucol    ] = h0;
      out[s_*512 + ucol + 1] = h1;
    }

    // drain our stores (global visibility), block-wide, then flag
    asm volatile("s_waitcnt vmcnt(0)" ::: "memory");
    __syncthreads();
    if (tid == 0)
      __hip_atomic_store(&flag[k<<5], (unsigned)(t+1),
                         __ATOMIC_RELAXED, __HIP_MEMORY_SCOPE_AGENT);
  }

  cst[s_*512 + ucol    ] = c0;
  cst[s_*512 + ucol + 1] = c1;
}

// ---------------- launch ----------------
extern "C" void kernel_launch(void* const* d_in, const int* in_sizes, int n_in,
                              void* d_out, int out_size, void* d_ws, size_t ws_size,
                              hipStream_t stream)
{
  const float* x   = (const float*)d_in[0];
  const float* Wih = (const float*)d_in[1];
  const float* Whh = (const float*)d_in[2];
  const float* bih = (const float*)d_in[3];
  const float* bhh = (const float*)d_in[4];
  float* out = (float*)d_out;

  char* ws = (char*)d_ws;
  const size_t XPB = (size_t)CHUNK*32*2048*2;          // 16,777,216 per buffer
  unsigned short* xp0  = (unsigned short*)ws;
  unsigned short* xp1  = (unsigned short*)(ws + XPB);
  unsigned short* Hbuf = (unsigned short*)(ws + 2*XPB);            // 2*32KB = 65536
  float*          cst  = (float*)(ws + 2*XPB + 65536);             // 64KB
  u32*            flag = (u32*)(ws + 2*XPB + 65536 + 65536);       // 32*128B = 4KB

  // zero Hbuf (h_0 = 0) + c-state + flags; every launch (replay-safe)
  (void)hipMemsetAsync(Hbuf, 0, 65536 + 65536 + 4096, stream);

  lstm_p1<<<dim3(32, CHUNK*32/64), 256, 0, stream>>>(x, Wih, bih, bhh, xp0, 0);

  for (int c=0; c<NCHUNK; ++c){
    unsigned short* xc = (c & 1) ? xp1 : xp0;
    unsigned short* xn = (c & 1) ? xp0 : xp1;
    lstm_fused<<<256, 256, 0, stream>>>(xc, x, Wih, bih, bhh, xn, Whh,
                                        Hbuf, cst, flag, out, c*CHUNK,
                                        (c < NCHUNK-1) ? 1 : 0);
  }
}